// Round 4
// baseline (349.967 us; speedup 1.0000x reference)
//
#include <hip/hip_runtime.h>

// B=256, T=2048, F=64, U=10 LSTM (Keras gates i,f,g,o; softsign cell act).
// R4: scan chain-depth reduction. Instead of activating per-gate-lane and
// DPP-broadcasting the ACTIVATIONS (cndmask+DPP+cross-gate product after the
// transcendental), broadcast the PRE-activations zz with 4 quad-DPPs at depth
// 1 and let every lane redundantly compute all four gate activations locally.
// Removes 2 cndmasks + post-trans DPP from the dependent chain (11->9 levels
// after zz); matvec as 4 chains + tree (depth 5 vs 6). Redundant per-lane
// trans work (~+3 exp2/+3 rcp) is free: solo-wave SIMD stall slots absorb it
// (R2 datum: 2x issue cost only +64% time). Producers unchanged from R3
// (chunk pairs as float2 [t2][col]; scan preloads whole chunk to registers).
#define B_ 256
#define T_ 2048
#define F_ 64
#define U_ 10
#define G_ 40
#define CH 32          // timesteps per chunk
#define CH2 (CH / 2)   // float2 pairs per chunk = 16
#define NCH (T_ / CH)  // 64
#define NLOG2E (-1.44269504088896340736f)

__device__ __forceinline__ float rcp_f(float x) { return __builtin_amdgcn_rcpf(x); }
__device__ __forceinline__ float exp2_f(float x) { return __builtin_amdgcn_exp2f(x); }
__device__ __forceinline__ float rdlane_f(float v, int l) {
  return __int_as_float(__builtin_amdgcn_readlane(__float_as_int(v), l));
}
template <int CTRL>
__device__ __forceinline__ float qbcast(float v) {  // quad_perm broadcast
  return __int_as_float(
      __builtin_amdgcn_update_dpp(0, __float_as_int(v), CTRL, 0xF, 0xF, true));
}
__device__ __forceinline__ void gload_lds16(const float* g, float* l) {
  // lane i's 16B lands at l + i*16; g is per-lane (contiguous across wave)
  __builtin_amdgcn_global_load_lds(
      (const __attribute__((address_space(1))) void*)g,
      (__attribute__((address_space(3))) void*)l, 16, 0, 0);
}

__global__ __launch_bounds__(256, 1) void lstm_fused(
    const float* __restrict__ x, const float* __restrict__ W,
    const float* __restrict__ R, const float* __restrict__ bias,
    const float* __restrict__ dw, const float* __restrict__ db,
    float* __restrict__ out) {
  __shared__ float xb[2][CH * F_];    // 2 x 8 KB x-chunk buffers (DMA target)
  __shared__ float2 zb[2][CH2 * G_];  // 2 x 5 KB z pair-buffers [t2][col]
  const int b = blockIdx.x;
  const int tid = threadIdx.x;
  const int wave = tid >> 6;
  const int lane = tid & 63;
  const float* xbase = x + (size_t)b * T_ * F_;

  if (wave == 0) {
    // ---------------- scan wave ----------------
    __builtin_amdgcn_s_setprio(3);
    const int L = (lane < G_) ? lane : (G_ - 1);
    const int u = L >> 2, gate = L & 3;
    const int col = gate * U_ + u;
    const float sc = (gate == 2) ? 1.f : NLOG2E;  // sigmoid cols scaled
    float Rc[U_];
    #pragma unroll
    for (int j = 0; j < U_; ++j) Rc[j] = R[j * G_ + col] * sc;
    const float dwu = dw[u];
    const float db0 = db[0];
    float h = 0.f, c = 0.f;

    // one timestep; zseed = (pre-scaled) z for this lane's column
    auto step = [&](float zseed) {
      float h0 = rdlane_f(h, 0),  h1 = rdlane_f(h, 4),  h2 = rdlane_f(h, 8);
      float h3 = rdlane_f(h, 12), h4 = rdlane_f(h, 16), h5 = rdlane_f(h, 20);
      float h6 = rdlane_f(h, 24), h7 = rdlane_f(h, 28);
      float h8 = rdlane_f(h, 32), h9 = rdlane_f(h, 36);
      // 4-chain matvec + tree combine: depth 3 fma + 2 add
      float q0 = fmaf(h0, Rc[0], zseed);
      q0 = fmaf(h1, Rc[1], q0);
      q0 = fmaf(h2, Rc[2], q0);
      float q1 = h3 * Rc[3];
      q1 = fmaf(h4, Rc[4], q1);
      q1 = fmaf(h5, Rc[5], q1);
      float q2 = h6 * Rc[6];
      q2 = fmaf(h7, Rc[7], q2);
      float q3 = h8 * Rc[8];
      q3 = fmaf(h9, Rc[9], q3);
      float zz = (q0 + q1) + (q2 + q3);
      // gather all four gate pre-activations of this unit (depth-1 DPP);
      // zi,zf,zo arrive pre-scaled by -log2e (producer/Rc scaling), zg raw.
      float zi = qbcast<0x00>(zz);
      float zf = qbcast<0x55>(zz);
      float zg = qbcast<0xAA>(zz);
      float zo = qbcast<0xFF>(zz);
      // all gate activations computed locally in every lane (redundant but
      // off-chain-free): sigmoid = rcp(1+exp2(zs)), softsign local.
      float ei = exp2_f(zi);
      float ef = exp2_f(zf);
      float eo = exp2_f(zo);
      float ri = rcp_f(1.f + ei);
      float rf = rcp_f(1.f + ef);
      float ro = rcp_f(1.f + eo);
      float rg = rcp_f(1.f + __builtin_fabsf(zg));
      float g = zg * rg;
      float ig = ri * g;
      c = fmaf(rf, c, ig);
      float oc = ro * c;                  // parallel with den
      float den = 1.f + __builtin_fabsf(c);
      h = oc * rcp_f(den);                // o * softsign(c)
    };

    __syncthreads();  // B-pre1: x(0),x(1) DMA complete
    __syncthreads();  // B-pre2: z(0) produced
    for (int cc = 0; cc < NCH; ++cc) {
      const float2* zp = zb[cc & 1] + L;
      float2 sd[CH2];
      #pragma unroll
      for (int k = 0; k < CH2; ++k) sd[k] = zp[k * G_];  // 16x ds_read_b64
      #pragma unroll
      for (int k = 0; k < CH2; ++k) {  // 32 steps, fully unrolled, reg-only
        step(sd[k].x);
        step(sd[k].y);
      }
      __syncthreads();  // B(cc)
    }
    // epilogue: logit = sum_u h[u]*dw[u] + db; out = sigmoid(logit)
    float p = h * dwu;
    float logit = db0;
    #pragma unroll
    for (int j = 0; j < U_; ++j) logit += rdlane_f(p, 4 * j);
    if (lane == 0) out[b] = rcp_f(1.f + __expf(-logit));
  } else {
    // ---------------- producer waves (1..3) ----------------
    const int p0 = tid - 64;                 // 0..191
    const int p = (p0 < 160) ? p0 : 159;
    const bool act = (p0 < 160);
    const int s = p % G_;                    // column slot 0..39
    const int tp = p / G_;                   // t2-slot 0..3
    const int u = s >> 2, gate = s & 3;
    const int col = gate * U_ + u;
    const int pw = wave - 1;                 // 0..2
    const float scp = (gate == 2) ? 1.f : NLOG2E;  // pre-scale sigmoid cols
    float wc[F_];
    #pragma unroll
    for (int k = 0; k < F_; ++k) wc[k] = W[k * G_ + col];
    const float bcol = bias[col];

    auto load_x = [&](int cx) {  // DMA x chunk cx -> xb[cx&1] (8 KB, 8 instr)
      const float* g = xbase + (size_t)cx * CH * F_;
      float* l = xb[cx & 1];
      for (int i = pw; i < 8; i += 3)
        gload_lds16(g + i * 256 + lane * 4, l + i * 256);
    };
    auto dot = [&](const float* xr) -> float {  // dot(x_row, W[:,col]) + bias
      const float4* row4 = (const float4*)xr;
      float z0 = bcol, z1 = 0.f, z2 = 0.f, z3 = 0.f;
      #pragma unroll
      for (int j = 0; j < 16; j += 4) {     // compile-time indices only!
        float4 a0 = row4[j], a1 = row4[j + 1], a2 = row4[j + 2], a3 = row4[j + 3];
        z0 = fmaf(a0.x, wc[4*j+0], z0);  z0 = fmaf(a0.y, wc[4*j+1], z0);
        z0 = fmaf(a0.z, wc[4*j+2], z0);  z0 = fmaf(a0.w, wc[4*j+3], z0);
        z1 = fmaf(a1.x, wc[4*j+4], z1);  z1 = fmaf(a1.y, wc[4*j+5], z1);
        z1 = fmaf(a1.z, wc[4*j+6], z1);  z1 = fmaf(a1.w, wc[4*j+7], z1);
        z2 = fmaf(a2.x, wc[4*j+8], z2);  z2 = fmaf(a2.y, wc[4*j+9], z2);
        z2 = fmaf(a2.z, wc[4*j+10], z2); z2 = fmaf(a2.w, wc[4*j+11], z2);
        z3 = fmaf(a3.x, wc[4*j+12], z3); z3 = fmaf(a3.y, wc[4*j+13], z3);
        z3 = fmaf(a3.z, wc[4*j+14], z3); z3 = fmaf(a3.w, wc[4*j+15], z3);
      }
      return ((z0 + z1) + (z2 + z3)) * scp;
    };
    auto produce = [&](int tc) {  // z chunk tc: xb[tc&1] -> zb[tc&1] (pairs)
      const float* xr = xb[tc & 1];
      float2* zrow = zb[tc & 1];
      #pragma unroll
      for (int k = 0; k < 4; ++k) {          // 4 t2-pairs per lane
        const int t2 = tp + 4 * k;           // 0..15
        float zE = dot(xr + (2 * t2) * F_);
        float zO = dot(xr + (2 * t2 + 1) * F_);
        if (act) zrow[t2 * G_ + s] = make_float2(zE, zO);
      }
    };

    load_x(0);
    load_x(1);
    __syncthreads();  // B-pre1 (barrier drains vmcnt -> DMA visible)
    produce(0);
    __syncthreads();  // B-pre2
    for (int cc = 0; cc < NCH; ++cc) {
      if (cc + 2 < NCH) load_x(cc + 2);
      if (cc + 1 < NCH) produce(cc + 1);
      __syncthreads();  // B(cc)
    }
  }
}

extern "C" void kernel_launch(void* const* d_in, const int* in_sizes, int n_in,
                              void* d_out, int out_size, void* d_ws, size_t ws_size,
                              hipStream_t stream) {
  const float* x    = (const float*)d_in[0];  // [256,2048,64]
  const float* W    = (const float*)d_in[1];  // [64,40]
  const float* R    = (const float*)d_in[2];  // [10,40]
  const float* bias = (const float*)d_in[3];  // [40]
  const float* dw   = (const float*)d_in[4];  // [10,1]
  const float* db   = (const float*)d_in[5];  // [1]
  float* out = (float*)d_out;                 // [256]
  (void)d_ws; (void)ws_size; (void)in_sizes; (void)n_in; (void)out_size;
  lstm_fused<<<B_, 256, 0, stream>>>(x, W, R, bias, dw, db, out);
}

// Round 6
// 329.239 us; speedup vs baseline: 1.0630x; 1.0630x over previous
//
#include <hip/hip_runtime.h>

// B=256, T=2048, F=64, U=10 LSTM (Keras gates i,f,g,o; softsign cell act).
// R6 = R3 (best: 204us kernel) + trans-neutral micro-levers (R5 re-run; R5's
// bench died in infra, not kernel):
//  * CH=64 (was 32): halves barrier count + per-chunk LDS burst-head stalls.
//    Scan preloads the chunk in TWO half-bursts of 16 float2 pairs (issue
//    reads for half B, compute half A) -- keeps VGPR ~R3's 104, small body.
//  * 4-chain matvec with zseed folded into chain 0: depth 5 from readlanes.
// Ledger from R1-R4: trans ops cost ~11 cyc each on the solo scan wave (R4:
// +5 trans = +55 cyc/step) -- never add trans. Dual-batch blocks can never
// win (wall = 2048 x per-step latency at any grid). Per-step LDS/bookkeeping
// removal was R3's -7.5%. Scan chain is the entire kernel.
#define B_ 256
#define T_ 2048
#define F_ 64
#define U_ 10
#define G_ 40
#define CH 64          // timesteps per chunk
#define CH2 (CH / 2)   // float2 pairs per chunk = 32
#define HB 16          // pairs per half-burst
#define NCH (T_ / CH)  // 32
#define NLOG2E (-1.44269504088896340736f)

__device__ __forceinline__ float rcp_f(float x) { return __builtin_amdgcn_rcpf(x); }
__device__ __forceinline__ float exp2_f(float x) { return __builtin_amdgcn_exp2f(x); }
__device__ __forceinline__ float rdlane_f(float v, int l) {
  return __int_as_float(__builtin_amdgcn_readlane(__float_as_int(v), l));
}
template <int CTRL>
__device__ __forceinline__ float qbcast(float v) {  // quad_perm broadcast
  return __int_as_float(
      __builtin_amdgcn_update_dpp(0, __float_as_int(v), CTRL, 0xF, 0xF, true));
}
__device__ __forceinline__ void gload_lds16(const float* g, float* l) {
  // lane i's 16B lands at l + i*16; g is per-lane (contiguous across wave)
  __builtin_amdgcn_global_load_lds(
      (const __attribute__((address_space(1))) void*)g,
      (__attribute__((address_space(3))) void*)l, 16, 0, 0);
}

__global__ __launch_bounds__(256, 1) void lstm_fused(
    const float* __restrict__ x, const float* __restrict__ W,
    const float* __restrict__ R, const float* __restrict__ bias,
    const float* __restrict__ dw, const float* __restrict__ db,
    float* __restrict__ out) {
  __shared__ float xb[2][CH * F_];    // 2 x 16 KB x-chunk buffers (DMA target)
  __shared__ float2 zb[2][CH2 * G_];  // 2 x 10 KB z pair-buffers [t2][col]
  const int b = blockIdx.x;
  const int tid = threadIdx.x;
  const int wave = tid >> 6;
  const int lane = tid & 63;
  const float* xbase = x + (size_t)b * T_ * F_;

  if (wave == 0) {
    // ---------------- scan wave ----------------
    __builtin_amdgcn_s_setprio(3);
    const int L = (lane < G_) ? lane : (G_ - 1);
    const int u = L >> 2, gate = L & 3;
    const int col = gate * U_ + u;
    const float sc = (gate == 2) ? 1.f : NLOG2E;  // sigmoid cols scaled
    float Rc[U_];
    #pragma unroll
    for (int j = 0; j < U_; ++j) Rc[j] = R[j * G_ + col] * sc;
    const float dwu = dw[u];
    const float db0 = db[0];
    float h = 0.f, c = 0.f;

    // one timestep; zseed = (pre-scaled) z for this lane's column
    auto step = [&](float zseed) {
      float h0 = rdlane_f(h, 0),  h1 = rdlane_f(h, 4),  h2 = rdlane_f(h, 8);
      float h3 = rdlane_f(h, 12), h4 = rdlane_f(h, 16), h5 = rdlane_f(h, 20);
      float h6 = rdlane_f(h, 24), h7 = rdlane_f(h, 28);
      float h8 = rdlane_f(h, 32), h9 = rdlane_f(h, 36);
      // 4-chain matvec, zseed folded into chain 0: depth 3 fma + 2 add
      float q0 = fmaf(h0, Rc[0], zseed);
      q0 = fmaf(h1, Rc[1], q0);
      q0 = fmaf(h2, Rc[2], q0);
      float q1 = h3 * Rc[3];
      q1 = fmaf(h4, Rc[4], q1);
      q1 = fmaf(h5, Rc[5], q1);
      float q2 = h6 * Rc[6];
      q2 = fmaf(h7, Rc[7], q2);
      float q3 = h8 * Rc[8];
      q3 = fmaf(h9, Rc[9], q3);
      float zz = (q0 + q1) + (q2 + q3);
      // shared-rcp activation: sigmoid lanes zz = -log2e*z -> e^{-z}=exp2(zz)
      float e = exp2_f(zz);
      float t = (gate == 2) ? __builtin_fabsf(zz) : e;
      float r = rcp_f(1.f + t);
      float a = (gate == 2) ? zz * r : r;
      float ai = qbcast<0x00>(a);
      float af = qbcast<0x55>(a);
      float ag = qbcast<0xAA>(a);
      float ao = qbcast<0xFF>(a);
      c = fmaf(af, c, ai * ag);
      float oc = ao * c;                  // parallel with den
      float den = 1.f + __builtin_fabsf(c);
      h = oc * rcp_f(den);                // o * softsign(c)
    };

    __syncthreads();  // B-pre1: x(0),x(1) DMA complete
    __syncthreads();  // B-pre2: z(0) produced
    for (int cc = 0; cc < NCH; ++cc) {
      const float2* zp = zb[cc & 1] + L;
      float2 sd[HB];
      #pragma unroll
      for (int k = 0; k < HB; ++k) sd[k] = zp[k * G_];  // half A: 16 reads
      #pragma unroll
      for (int k = 0; k < HB; ++k) {   // 32 steps from half A
        float2 s2 = sd[k];
        sd[k] = zp[(k + HB) * G_];     // refill slot with half B (issued
        step(s2.x);                    //  early; consumed 32+ steps later)
        step(s2.y);
      }
      #pragma unroll
      for (int k = 0; k < HB; ++k) {   // 32 steps from half B
        step(sd[k].x);
        step(sd[k].y);
      }
      __syncthreads();  // B(cc)
    }
    // epilogue: logit = sum_u h[u]*dw[u] + db; out = sigmoid(logit)
    float p = h * dwu;
    float logit = db0;
    #pragma unroll
    for (int j = 0; j < U_; ++j) logit += rdlane_f(p, 4 * j);
    if (lane == 0) out[b] = rcp_f(1.f + __expf(-logit));
  } else {
    // ---------------- producer waves (1..3) ----------------
    const int p0 = tid - 64;                 // 0..191
    const int p = (p0 < 160) ? p0 : 159;
    const bool act = (p0 < 160);
    const int s = p % G_;                    // column slot 0..39
    const int tp = p / G_;                   // t2-slot 0..3
    const int u = s >> 2, gate = s & 3;
    const int col = gate * U_ + u;
    const int pw = wave - 1;                 // 0..2
    const float scp = (gate == 2) ? 1.f : NLOG2E;  // pre-scale sigmoid cols
    float wc[F_];
    #pragma unroll
    for (int k = 0; k < F_; ++k) wc[k] = W[k * G_ + col];
    const float bcol = bias[col];

    auto load_x = [&](int cx) {  // DMA x chunk cx -> xb[cx&1] (16 KB, 16 instr)
      const float* g = xbase + (size_t)cx * CH * F_;
      float* l = xb[cx & 1];
      for (int i = pw; i < 16; i += 3)
        gload_lds16(g + i * 256 + lane * 4, l + i * 256);
    };
    auto dot = [&](const float* xr) -> float {  // dot(x_row, W[:,col]) + bias
      const float4* row4 = (const float4*)xr;
      float z0 = bcol, z1 = 0.f, z2 = 0.f, z3 = 0.f;
      #pragma unroll
      for (int j = 0; j < 16; j += 4) {     // compile-time indices only!
        float4 a0 = row4[j], a1 = row4[j + 1], a2 = row4[j + 2], a3 = row4[j + 3];
        z0 = fmaf(a0.x, wc[4*j+0], z0);  z0 = fmaf(a0.y, wc[4*j+1], z0);
        z0 = fmaf(a0.z, wc[4*j+2], z0);  z0 = fmaf(a0.w, wc[4*j+3], z0);
        z1 = fmaf(a1.x, wc[4*j+4], z1);  z1 = fmaf(a1.y, wc[4*j+5], z1);
        z1 = fmaf(a1.z, wc[4*j+6], z1);  z1 = fmaf(a1.w, wc[4*j+7], z1);
        z2 = fmaf(a2.x, wc[4*j+8], z2);  z2 = fmaf(a2.y, wc[4*j+9], z2);
        z2 = fmaf(a2.z, wc[4*j+10], z2); z2 = fmaf(a2.w, wc[4*j+11], z2);
        z3 = fmaf(a3.x, wc[4*j+12], z3); z3 = fmaf(a3.y, wc[4*j+13], z3);
        z3 = fmaf(a3.z, wc[4*j+14], z3); z3 = fmaf(a3.w, wc[4*j+15], z3);
      }
      return ((z0 + z1) + (z2 + z3)) * scp;
    };
    auto produce = [&](int tc) {  // z chunk tc: xb[tc&1] -> zb[tc&1] (pairs)
      const float* xr = xb[tc & 1];
      float2* zrow = zb[tc & 1];
      #pragma unroll
      for (int k = 0; k < 8; ++k) {          // 8 t2-pairs per lane
        const int t2 = tp + 4 * k;           // 0..31
        float zE = dot(xr + (2 * t2) * F_);
        float zO = dot(xr + (2 * t2 + 1) * F_);
        if (act) zrow[t2 * G_ + s] = make_float2(zE, zO);
      }
    };

    load_x(0);
    load_x(1);
    __syncthreads();  // B-pre1 (barrier drains vmcnt -> DMA visible)
    produce(0);
    __syncthreads();  // B-pre2
    for (int cc = 0; cc < NCH; ++cc) {
      if (cc + 2 < NCH) load_x(cc + 2);
      if (cc + 1 < NCH) produce(cc + 1);
      __syncthreads();  // B(cc)
    }
  }
}

extern "C" void kernel_launch(void* const* d_in, const int* in_sizes, int n_in,
                              void* d_out, int out_size, void* d_ws, size_t ws_size,
                              hipStream_t stream) {
  const float* x    = (const float*)d_in[0];  // [256,2048,64]
  const float* W    = (const float*)d_in[1];  // [64,40]
  const float* R    = (const float*)d_in[2];  // [10,40]
  const float* bias = (const float*)d_in[3];  // [40]
  const float* dw   = (const float*)d_in[4];  // [10,1]
  const float* db   = (const float*)d_in[5];  // [1]
  float* out = (float*)d_out;                 // [256]
  (void)d_ws; (void)ws_size; (void)in_sizes; (void)n_in; (void)out_size;
  lstm_fused<<<B_, 256, 0, stream>>>(x, W, R, bias, dw, db, out);
}